// Round 1
// baseline (467.279 us; speedup 1.0000x reference)
//
#include <hip/hip_runtime.h>

#define IMG 28
#define NU 96
#define S (IMG * NU)        // 2688
#define S4 (S / 4)          // 672
#define NU2 (NU * NU)       // 9216
#define TILE4 (IMG * IMG / 4)  // 196 float4 per 28x28 tile

// ---------------------------------------------------------------------------
// Kernel 1: per-unit sum of (som - tiled_x)^2 / running_variance
// one wave (64 lanes) per unit (u,v); float4 loads; wave shuffle reduce
// ---------------------------------------------------------------------------
__global__ void unit_map_kernel(const float* __restrict__ som,
                                const float* __restrict__ rv,
                                const float* __restrict__ x,
                                float* __restrict__ unit_map) {
    int b = blockIdx.x;            // unit id in [0, 9216)
    int u = b / NU, v = b % NU;
    int lane = threadIdx.x;        // 0..63
    const float4* som4 = (const float4*)som;
    const float4* rv4  = (const float4*)rv;
    const float4* x4p  = (const float4*)x;
    int base4 = (u * IMG) * S4 + (v * IMG) / 4;
    float acc = 0.f;
    // 196 float4 groups per tile; 28 = 7 float4 per row
    for (int e = lane; e < TILE4; e += 64) {
        int r = e / 7, f = e % 7;
        float4 s4 = som4[base4 + r * S4 + f];
        float4 v4 = rv4 [base4 + r * S4 + f];
        float4 xx = x4p[r * 7 + f];
        float d0 = s4.x - xx.x, d1 = s4.y - xx.y;
        float d2 = s4.z - xx.z, d3 = s4.w - xx.w;
        acc += d0 * d0 / v4.x + d1 * d1 / v4.y + d2 * d2 / v4.z + d3 * d3 / v4.w;
    }
    for (int off = 32; off > 0; off >>= 1)
        acc += __shfl_down(acc, off, 64);
    if (lane == 0) unit_map[b] = acc;
}

// ---------------------------------------------------------------------------
// Kernel 2: argmin over unit_map (first-occurrence tie-break, matching
// jnp.argmin), then compute per-unit final_modifier and variance_alpha
// ---------------------------------------------------------------------------
__global__ void bmu_kernel(const float* __restrict__ unit_map,
                           const float* __restrict__ lr_mat,
                           const float* __restrict__ rad_mat,
                           const float* __restrict__ cart,
                           float* __restrict__ fm_arr,
                           float* __restrict__ va_arr) {
    __shared__ float svals[256];
    __shared__ int   sidx[256];
    __shared__ float sc[3];   // r, dist_mod, constant
    __shared__ int   sbij;
    int t = threadIdx.x;
    float bestv = 3.4e38f;
    int   besti = 0x7fffffff;
    for (int e = t; e < NU2; e += 256) {
        float v = unit_map[e];
        if (v < bestv) { bestv = v; besti = e; }   // strict < keeps earliest
    }
    svals[t] = bestv; sidx[t] = besti;
    __syncthreads();
    for (int s = 128; s > 0; s >>= 1) {
        if (t < s) {
            float ov = svals[t + s]; int oi = sidx[t + s];
            if (ov < svals[t] || (ov == svals[t] && oi < sidx[t])) {
                svals[t] = ov; sidx[t] = oi;
            }
        }
        __syncthreads();
    }
    if (t == 0) {
        int flat = sidx[0];
        float r  = rad_mat[flat];
        float lr = lr_mat[flat];
        float dist_mod = 1.f / (2.f * r * r);
        float constant = -logf(1e-8f / lr) / dist_mod;
        sc[0] = r; sc[1] = dist_mod; sc[2] = constant;
        sbij = flat;   // flat == bi*96 + bj
    }
    __syncthreads();
    float r = sc[0], dist_mod = sc[1], constant = sc[2];
    int bij = sbij;
    for (int e = t; e < NU2; e += 256) {
        // cart[u, v, bi, bj] with (u,v) flat == e -> cart[e*9216 + bi*96+bj]
        float d    = cart[(long)e * NU2 + bij];
        float mask = (d > r) ? 0.f : 1.f;
        float fm   = mask * lr_mat[e] * expf(-d * dist_mod);
        float va_raw = (0.9f - 0.5f) + 1.f / (1.f + expf(-d / constant));
        float va = fminf(fmaxf(mask * va_raw + (1.f - mask), 0.f), 1.f);
        fm_arr[e] = fm;
        va_arr[e] = va;
    }
}

// ---------------------------------------------------------------------------
// Kernel 3: elementwise update, float4 over columns.
// 28 = 4*7 so a float4 group never crosses a unit or x-tile boundary.
// ---------------------------------------------------------------------------
__global__ void update_kernel(const float* __restrict__ som,
                              const float* __restrict__ rv,
                              const float* __restrict__ x,
                              const float* __restrict__ fm_arr,
                              const float* __restrict__ va_arr,
                              float* __restrict__ out) {
    int idx4 = blockIdx.x * blockDim.x + threadIdx.x;  // [0, S*S4)
    int j4 = idx4 % S4;
    int i  = idx4 / S4;
    int u  = i / IMG;
    int v  = j4 / 7;          // (4*j4)/28
    int xr = i % IMG;
    int xf = j4 % 7;
    float4 s4 = ((const float4*)som)[idx4];
    float4 r4 = ((const float4*)rv)[idx4];
    float4 x4 = ((const float4*)x)[xr * 7 + xf];
    int unit = u * NU + v;
    float fm = fm_arr[unit];
    float va = va_arr[unit];
    float4 sn, vn;
    {
        sn.x = fminf(fmaxf(s4.x + fm * (x4.x - s4.x), 0.f), 1.f);
        float dd = x4.x - sn.x; vn.x = va * r4.x + (1.f - va) * dd * dd;
        sn.y = fminf(fmaxf(s4.y + fm * (x4.y - s4.y), 0.f), 1.f);
        dd = x4.y - sn.y; vn.y = va * r4.y + (1.f - va) * dd * dd;
        sn.z = fminf(fmaxf(s4.z + fm * (x4.z - s4.z), 0.f), 1.f);
        dd = x4.z - sn.z; vn.z = va * r4.z + (1.f - va) * dd * dd;
        sn.w = fminf(fmaxf(s4.w + fm * (x4.w - s4.w), 0.f), 1.f);
        dd = x4.w - sn.w; vn.w = va * r4.w + (1.f - va) * dd * dd;
    }
    ((float4*)out)[idx4] = sn;               // som_new
    ((float4*)out)[S * S4 + idx4] = vn;      // var_new
}

extern "C" void kernel_launch(void* const* d_in, const int* in_sizes, int n_in,
                              void* d_out, int out_size, void* d_ws, size_t ws_size,
                              hipStream_t stream) {
    const float* som  = (const float*)d_in[0];
    const float* rv   = (const float*)d_in[1];
    const float* lr   = (const float*)d_in[2];
    const float* rad  = (const float*)d_in[3];
    const float* cart = (const float*)d_in[4];
    const float* x    = (const float*)d_in[5];
    float* out = (float*)d_out;

    float* unit_map = (float*)d_ws;
    float* fm_arr   = unit_map + NU2;
    float* va_arr   = fm_arr + NU2;

    unit_map_kernel<<<NU2, 64, 0, stream>>>(som, rv, x, unit_map);
    bmu_kernel<<<1, 256, 0, stream>>>(unit_map, lr, rad, cart, fm_arr, va_arr);
    // S*S4 / 256 = 2688*672/256 = 7056 blocks exactly
    update_kernel<<<7056, 256, 0, stream>>>(som, rv, x, fm_arr, va_arr, out);
}

// Round 2
// 452.724 us; speedup vs baseline: 1.0322x; 1.0322x over previous
//
#include <hip/hip_runtime.h>

#define IMG 28
#define NU 96
#define S (IMG * NU)        // 2688
#define S4 (S / 4)          // 672
#define NU2 (NU * NU)       // 9216
#define TILE4 (IMG * IMG / 4)  // 196 float4 per 28x28 tile

// ---------------------------------------------------------------------------
// Kernel 1: per-unit sum of (som - tiled_x)^2 / running_variance
// one wave (64 lanes) per unit (u,v); float4 loads; wave shuffle reduce
// ---------------------------------------------------------------------------
__global__ void unit_map_kernel(const float* __restrict__ som,
                                const float* __restrict__ rv,
                                const float* __restrict__ x,
                                float* __restrict__ unit_map) {
    int b = blockIdx.x;            // unit id in [0, 9216)
    int u = b / NU, v = b % NU;
    int lane = threadIdx.x;        // 0..63
    const float4* som4 = (const float4*)som;
    const float4* rv4  = (const float4*)rv;
    const float4* x4p  = (const float4*)x;
    int base4 = (u * IMG) * S4 + (v * IMG) / 4;
    float acc = 0.f;
    // 196 float4 groups per tile; 28 = 7 float4 per row
    for (int e = lane; e < TILE4; e += 64) {
        int r = e / 7, f = e % 7;
        float4 s4 = som4[base4 + r * S4 + f];
        float4 v4 = rv4 [base4 + r * S4 + f];
        float4 xx = x4p[r * 7 + f];
        float d0 = s4.x - xx.x, d1 = s4.y - xx.y;
        float d2 = s4.z - xx.z, d3 = s4.w - xx.w;
        acc += d0 * d0 / v4.x + d1 * d1 / v4.y + d2 * d2 / v4.z + d3 * d3 / v4.w;
    }
    for (int off = 32; off > 0; off >>= 1)
        acc += __shfl_down(acc, off, 64);
    if (lane == 0) unit_map[b] = acc;
}

// ---------------------------------------------------------------------------
// Kernel 2: argmin over unit_map (first-occurrence tie-break, matching
// jnp.argmin), then compute per-unit final_modifier and variance_alpha.
// Distance is computed analytically: cart[u,v,bi,bj] == sqrtf((u-bi)^2 +
// (v-bj)^2) exactly (integer squares exact in fp32, IEEE sqrt correctly
// rounded) -> no gather from the cold 340 MB cart array.
// ---------------------------------------------------------------------------
__global__ void bmu_kernel(const float* __restrict__ unit_map,
                           const float* __restrict__ lr_mat,
                           const float* __restrict__ rad_mat,
                           float* __restrict__ fm_arr,
                           float* __restrict__ va_arr) {
    __shared__ float svals[256];
    __shared__ int   sidx[256];
    __shared__ float sc[3];   // r, dist_mod, constant
    __shared__ int   sbij;
    int t = threadIdx.x;
    float bestv = 3.4e38f;
    int   besti = 0x7fffffff;
    for (int e = t; e < NU2; e += 256) {
        float v = unit_map[e];
        if (v < bestv) { bestv = v; besti = e; }   // strict < keeps earliest
    }
    svals[t] = bestv; sidx[t] = besti;
    __syncthreads();
    for (int s = 128; s > 0; s >>= 1) {
        if (t < s) {
            float ov = svals[t + s]; int oi = sidx[t + s];
            if (ov < svals[t] || (ov == svals[t] && oi < sidx[t])) {
                svals[t] = ov; sidx[t] = oi;
            }
        }
        __syncthreads();
    }
    if (t == 0) {
        int flat = sidx[0];
        float r  = rad_mat[flat];
        float lr = lr_mat[flat];
        float dist_mod = 1.f / (2.f * r * r);
        float constant = -logf(1e-8f / lr) / dist_mod;
        sc[0] = r; sc[1] = dist_mod; sc[2] = constant;
        sbij = flat;   // flat == bi*96 + bj
    }
    __syncthreads();
    float r = sc[0], dist_mod = sc[1], constant = sc[2];
    int bi = sbij / NU, bj = sbij % NU;
    for (int e = t; e < NU2; e += 256) {
        int u = e / NU, v = e % NU;
        float du = (float)(u - bi), dv = (float)(v - bj);
        float d  = sqrtf(du * du + dv * dv);
        float mask = (d > r) ? 0.f : 1.f;
        float fm   = mask * lr_mat[e] * expf(-d * dist_mod);
        float va_raw = (0.9f - 0.5f) + 1.f / (1.f + expf(-d / constant));
        float va = fminf(fmaxf(mask * va_raw + (1.f - mask), 0.f), 1.f);
        fm_arr[e] = fm;
        va_arr[e] = va;
    }
}

// ---------------------------------------------------------------------------
// Kernel 3: elementwise update, float4 over columns.
// 28 = 4*7 so a float4 group never crosses a unit or x-tile boundary.
// ---------------------------------------------------------------------------
__global__ void update_kernel(const float* __restrict__ som,
                              const float* __restrict__ rv,
                              const float* __restrict__ x,
                              const float* __restrict__ fm_arr,
                              const float* __restrict__ va_arr,
                              float* __restrict__ out) {
    int idx4 = blockIdx.x * blockDim.x + threadIdx.x;  // [0, S*S4)
    int j4 = idx4 % S4;
    int i  = idx4 / S4;
    int u  = i / IMG;
    int v  = j4 / 7;          // (4*j4)/28
    int xr = i % IMG;
    int xf = j4 % 7;
    float4 s4 = ((const float4*)som)[idx4];
    float4 r4 = ((const float4*)rv)[idx4];
    float4 x4 = ((const float4*)x)[xr * 7 + xf];
    int unit = u * NU + v;
    float fm = fm_arr[unit];
    float va = va_arr[unit];
    float4 sn, vn;
    {
        sn.x = fminf(fmaxf(s4.x + fm * (x4.x - s4.x), 0.f), 1.f);
        float dd = x4.x - sn.x; vn.x = va * r4.x + (1.f - va) * dd * dd;
        sn.y = fminf(fmaxf(s4.y + fm * (x4.y - s4.y), 0.f), 1.f);
        dd = x4.y - sn.y; vn.y = va * r4.y + (1.f - va) * dd * dd;
        sn.z = fminf(fmaxf(s4.z + fm * (x4.z - s4.z), 0.f), 1.f);
        dd = x4.z - sn.z; vn.z = va * r4.z + (1.f - va) * dd * dd;
        sn.w = fminf(fmaxf(s4.w + fm * (x4.w - s4.w), 0.f), 1.f);
        dd = x4.w - sn.w; vn.w = va * r4.w + (1.f - va) * dd * dd;
    }
    ((float4*)out)[idx4] = sn;               // som_new
    ((float4*)out)[S * S4 + idx4] = vn;      // var_new
}

extern "C" void kernel_launch(void* const* d_in, const int* in_sizes, int n_in,
                              void* d_out, int out_size, void* d_ws, size_t ws_size,
                              hipStream_t stream) {
    const float* som  = (const float*)d_in[0];
    const float* rv   = (const float*)d_in[1];
    const float* lr   = (const float*)d_in[2];
    const float* rad  = (const float*)d_in[3];
    // d_in[4] (cartesian_distances) no longer read — computed analytically
    const float* x    = (const float*)d_in[5];
    float* out = (float*)d_out;

    float* unit_map = (float*)d_ws;
    float* fm_arr   = unit_map + NU2;
    float* va_arr   = fm_arr + NU2;

    unit_map_kernel<<<NU2, 64, 0, stream>>>(som, rv, x, unit_map);
    bmu_kernel<<<1, 256, 0, stream>>>(unit_map, lr, rad, fm_arr, va_arr);
    // S*S4 / 256 = 2688*672/256 = 7056 blocks exactly
    update_kernel<<<7056, 256, 0, stream>>>(som, rv, x, fm_arr, va_arr, out);
}

// Round 3
// 437.922 us; speedup vs baseline: 1.0670x; 1.0338x over previous
//
#include <hip/hip_runtime.h>

#define IMG 28
#define NU 96
#define S (IMG * NU)        // 2688
#define S4 (S / 4)          // 672
#define NU2 (NU * NU)       // 9216
#define TILE4 (IMG * IMG / 4)  // 196 float4 per 28x28 tile

// ---------------------------------------------------------------------------
// Kernel 1: per-unit sum of (som - tiled_x)^2 / running_variance
// one wave (64 lanes) per unit (u,v); float4 loads; wave shuffle reduce
// ---------------------------------------------------------------------------
__global__ void unit_map_kernel(const float* __restrict__ som,
                                const float* __restrict__ rv,
                                const float* __restrict__ x,
                                float* __restrict__ unit_map) {
    int b = blockIdx.x;            // unit id in [0, 9216)
    int u = b / NU, v = b % NU;
    int lane = threadIdx.x;        // 0..63
    const float4* som4 = (const float4*)som;
    const float4* rv4  = (const float4*)rv;
    const float4* x4p  = (const float4*)x;
    int base4 = (u * IMG) * S4 + (v * IMG) / 4;
    float acc = 0.f;
    // 196 float4 groups per tile; 28 = 7 float4 per row
    for (int e = lane; e < TILE4; e += 64) {
        int r = e / 7, f = e % 7;
        float4 s4 = som4[base4 + r * S4 + f];
        float4 v4 = rv4 [base4 + r * S4 + f];
        float4 xx = x4p[r * 7 + f];
        float d0 = s4.x - xx.x, d1 = s4.y - xx.y;
        float d2 = s4.z - xx.z, d3 = s4.w - xx.w;
        acc += d0 * d0 / v4.x + d1 * d1 / v4.y + d2 * d2 / v4.z + d3 * d3 / v4.w;
    }
    for (int off = 32; off > 0; off >>= 1)
        acc += __shfl_down(acc, off, 64);
    if (lane == 0) unit_map[b] = acc;
}

// ---------------------------------------------------------------------------
// Kernel 2: pure argmin over unit_map (first-occurrence tie-break, matching
// jnp.argmin). Emits a 16-byte BMU record: {r, dist_mod, constant, bij}.
// ---------------------------------------------------------------------------
__global__ void bmu_kernel(const float* __restrict__ unit_map,
                           const float* __restrict__ lr_mat,
                           const float* __restrict__ rad_mat,
                           float* __restrict__ bmu_rec) {
    __shared__ float svals[1024];
    __shared__ int   sidx[1024];
    int t = threadIdx.x;
    float bestv = 3.4e38f;
    int   besti = 0x7fffffff;
    for (int e = t; e < NU2; e += 1024) {    // 9 iterations
        float v = unit_map[e];
        if (v < bestv) { bestv = v; besti = e; }   // strict < keeps earliest
    }
    svals[t] = bestv; sidx[t] = besti;
    __syncthreads();
    for (int s = 512; s > 0; s >>= 1) {
        if (t < s) {
            float ov = svals[t + s]; int oi = sidx[t + s];
            if (ov < svals[t] || (ov == svals[t] && oi < sidx[t])) {
                svals[t] = ov; sidx[t] = oi;
            }
        }
        __syncthreads();
    }
    if (t == 0) {
        int flat = sidx[0];                  // flat == bi*96 + bj
        float r  = rad_mat[flat];
        float lr = lr_mat[flat];
        float dist_mod = 1.f / (2.f * r * r);
        float constant = -logf(1e-8f / lr) / dist_mod;
        bmu_rec[0] = r;
        bmu_rec[1] = dist_mod;
        bmu_rec[2] = constant;
        bmu_rec[3] = __int_as_float(flat);
    }
}

// ---------------------------------------------------------------------------
// Kernel 3: elementwise update, float4 over columns. Per-thread computes its
// unit's final_modifier / variance_alpha inline from the BMU record:
// d = sqrtf((u-bi)^2+(v-bj)^2) is bit-identical to the cart input (integer
// squares exact in fp32, IEEE sqrt correctly rounded). ~25 extra VALU ops
// per thread, hidden under the 116 MB of memory traffic.
// 28 = 4*7 so a float4 group never crosses a unit or x-tile boundary.
// ---------------------------------------------------------------------------
__global__ void update_kernel(const float* __restrict__ som,
                              const float* __restrict__ rv,
                              const float* __restrict__ x,
                              const float* __restrict__ lr_mat,
                              const float* __restrict__ bmu_rec,
                              float* __restrict__ out) {
    int idx4 = blockIdx.x * blockDim.x + threadIdx.x;  // [0, S*S4)
    int j4 = idx4 % S4;
    int i  = idx4 / S4;
    int u  = i / IMG;
    int v  = j4 / 7;          // (4*j4)/28
    int xr = i % IMG;
    int xf = j4 % 7;

    float4 b4 = ((const float4*)bmu_rec)[0];   // uniform broadcast load
    float r = b4.x, dist_mod = b4.y, constant = b4.z;
    int bij = __float_as_int(b4.w);
    int bi = bij / NU, bj = bij % NU;

    int unit = u * NU + v;
    float du = (float)(u - bi), dv = (float)(v - bj);
    float d  = sqrtf(du * du + dv * dv);
    float mask = (d > r) ? 0.f : 1.f;
    float fm   = mask * lr_mat[unit] * expf(-d * dist_mod);
    float va_raw = 0.4f + 1.f / (1.f + expf(-d / constant));
    float va = fminf(fmaxf(mask * va_raw + (1.f - mask), 0.f), 1.f);

    float4 s4 = ((const float4*)som)[idx4];
    float4 r4 = ((const float4*)rv)[idx4];
    float4 x4 = ((const float4*)x)[xr * 7 + xf];
    float4 sn, vn;
    {
        sn.x = fminf(fmaxf(s4.x + fm * (x4.x - s4.x), 0.f), 1.f);
        float dd = x4.x - sn.x; vn.x = va * r4.x + (1.f - va) * dd * dd;
        sn.y = fminf(fmaxf(s4.y + fm * (x4.y - s4.y), 0.f), 1.f);
        dd = x4.y - sn.y; vn.y = va * r4.y + (1.f - va) * dd * dd;
        sn.z = fminf(fmaxf(s4.z + fm * (x4.z - s4.z), 0.f), 1.f);
        dd = x4.z - sn.z; vn.z = va * r4.z + (1.f - va) * dd * dd;
        sn.w = fminf(fmaxf(s4.w + fm * (x4.w - s4.w), 0.f), 1.f);
        dd = x4.w - sn.w; vn.w = va * r4.w + (1.f - va) * dd * dd;
    }
    ((float4*)out)[idx4] = sn;               // som_new
    ((float4*)out)[S * S4 + idx4] = vn;      // var_new
}

extern "C" void kernel_launch(void* const* d_in, const int* in_sizes, int n_in,
                              void* d_out, int out_size, void* d_ws, size_t ws_size,
                              hipStream_t stream) {
    const float* som  = (const float*)d_in[0];
    const float* rv   = (const float*)d_in[1];
    const float* lr   = (const float*)d_in[2];
    const float* rad  = (const float*)d_in[3];
    // d_in[4] (cartesian_distances) no longer read — computed analytically
    const float* x    = (const float*)d_in[5];
    float* out = (float*)d_out;

    float* unit_map = (float*)d_ws;
    float* bmu_rec  = unit_map + NU2;   // 4 floats, 16B-aligned

    unit_map_kernel<<<NU2, 64, 0, stream>>>(som, rv, x, unit_map);
    bmu_kernel<<<1, 1024, 0, stream>>>(unit_map, lr, rad, bmu_rec);
    // S*S4 / 256 = 2688*672/256 = 7056 blocks exactly
    update_kernel<<<7056, 256, 0, stream>>>(som, rv, x, lr, bmu_rec, out);
}